// Round 24
// baseline (897.510 us; speedup 1.0000x reference)
//
#include <hip/hip_runtime.h>
#include <math.h>

// Residual VQ, 4 stages, N=16384 rows, D=512, K=4096.
// Round 24: finish micro-opts (math untouched, r23 PASSED 820us):
//   1. Interleaved dual chain: both slots' exact chains in ONE 512-iter loop
//      (independent accumulators; shared r4 loads; non-qualifying slot aims
//      at codebook row 0, discarded). Wave runs the loop once, not twice.
//   2. T14 early-issue of combine fragments (rr rv4 + qout qo4) before the
//      slab sync -- their HBM latency hides under the front phase.
//   3. qout RMW uses prefetched qo4 (same add, same order).
// passA r18-verbatim; shortcut/reduce/combine/rsq r23-verbatim.
// Exact-math invariants (verified rounds 3-23): one fmaf per d, d=0..511
// ascending, per output; epilogue fl(fl(rsq-fl(2*dot))+cbsq) uncontracted;
// first-index ties; numpy pairwise rsq/cbsq tree; exact residual/q_ste chain.

namespace {
constexpr int N_ROWS     = 16384;
constexpr int DIM        = 512;
constexpr int K_CODES    = 4096;
constexpr int NUM_STAGES = 4;

constexpr int KTILES = 32;            // 128 codes per tile
constexpr float EPS  = 1e-3f;         // compaction margin (proven rounds 7-23)
constexpr float GAPF = 6e-4f;         // >= 2*delta shortcut gap (delta<=2.7e-4)
constexpr int CAP    = 2;             // compacted candidates per (row,tile)

// d_out layout (all read back as float32):
constexpr size_t Q_OFF    = 0;
constexpr size_t IDX_OFF  = (size_t)N_ROWS * DIM;                  // 8388608
constexpr size_t LOSS_OFF = IDX_OFF + (size_t)N_ROWS * NUM_STAGES; // 8454144

// ws layout (bytes), total ~62.3 MB:
constexpr size_t RES_OFF  = 0;                                    // 32 MB fp32 residual
constexpr size_t RH_OFF   = (size_t)N_ROWS * DIM * 4;             // +16 MB bf16 residual
constexpr size_t WH_OFF   = RH_OFF + (size_t)N_ROWS * DIM * 2;    // +4 MB bf16 codebook
constexpr size_t CBSQ_OFF = WH_OFF + (size_t)K_CODES * DIM * 2;   // +16 KB
constexpr size_t RSQ_OFF  = CBSQ_OFF + (size_t)K_CODES * 4;       // +64 KB
constexpr size_t PART_OFF = RSQ_OFF + (size_t)N_ROWS * 4;         // +2 MB tile mins [tile][row]
constexpr size_t GBUF_OFF = PART_OFF + (size_t)N_ROWS * KTILES * 4; // +8 MB [tile][row][CAP]

constexpr unsigned long long EMPTY_E = 0xFFFFFFFFFFFFFFFFull;
constexpr unsigned long long OVFL_E  = 0xFFFFFFFFFFFFFFFEull;
} // namespace

typedef short bf16x8 __attribute__((ext_vector_type(8)));
typedef float f32x4  __attribute__((ext_vector_type(4)));

typedef __attribute__((address_space(1))) const unsigned int glob_u32;
typedef __attribute__((address_space(3))) unsigned int lds_u32;

__device__ __forceinline__ unsigned short f2bf(float x) {   // RNE fp32->bf16
    unsigned int u = __float_as_uint(x);
    return (unsigned short)((u + 0x7fffu + ((u >> 16) & 1u)) >> 16);
}

// Register-based exact pairwise tree (64-lane): v8[i] = row[lane + i*64].
__device__ __forceinline__ float rowsq_tree(const float v8[8], int lane) {
#pragma clang fp contract(off)
    float P[4];
#pragma unroll
    for (int b = 0; b < 4; ++b) {
        float xa = v8[2 * b];
        float xb = v8[2 * b + 1];
        float sa = xa * xa;
        float sb = xb * xb;
        float R  = sa + sb;
        float t  = R + __shfl_down(R, 16, 64);
        float u  = t + __shfl_down(t, 32, 64);
        float a  = u + __shfl_down(u, 8, 64);
        float c  = a + __shfl_down(a, 4, 64);
        float d  = c + __shfl_down(c, 2, 64);
        P[b]     = d + __shfl_down(d, 1, 64);
    }
    float s01 = P[0] + P[1];
    float s23 = P[2] + P[3];
    return s01 + s23;
}

// Setup (fused): blocks 0..1023 -> cbsq + bf16 codebook; 1024..5119 -> init.
__global__ __launch_bounds__(256)
void setup_kernel(const float* __restrict__ cb, float* __restrict__ cb_sq,
                  unsigned short* __restrict__ wh, float* __restrict__ loss,
                  const float* __restrict__ input,
                  unsigned short* __restrict__ rh, float* __restrict__ rsq) {
    const int t    = threadIdx.x;
    const int lane = t & 63;
    const int sub  = t >> 6;
    if (blockIdx.x < 1024) {
        int k = blockIdx.x * 4 + sub;
        const float* row = cb + (size_t)k * DIM;
        unsigned short* whp = wh + (size_t)k * DIM;
        float v8[8];
#pragma unroll
        for (int i = 0; i < 8; ++i) {
            float v = row[lane + i * 64];
            v8[i] = v;
            whp[lane + i * 64] = f2bf(v);
        }
        float s = rowsq_tree(v8, lane);
        if (lane == 0) cb_sq[k] = s;
        if (k == 0 && lane == 0) *loss = 0.0f;
    } else {
        int row = (blockIdx.x - 1024) * 4 + sub;
        const float* x = input + (size_t)row * DIM;
        unsigned short* rhp = rh + (size_t)row * DIM;
        float v8[8];
#pragma unroll
        for (int i = 0; i < 8; ++i) {
            int d = lane + i * 64;
            float v = x[d];
            v8[i] = v;
            rhp[d] = f2bf(v);
        }
        float s = rowsq_tree(v8, lane);
        if (lane == 0) rsq[row] = s;
    }
}

// Pass A (r18-verbatim): 128x128x(BK=64) bf16 MFMA GEMM via global_load_lds
// with pre-swizzled source + XOR frag reads; epilogue candidate compaction.
__global__ __launch_bounds__(256, 2)
void passA_kernel(const unsigned short* __restrict__ rh,
                  const unsigned short* __restrict__ wh,
                  const float* __restrict__ cb_sq,
                  const float* __restrict__ rsq,
                  float* __restrict__ part,
                  unsigned long long* __restrict__ gbuf) {
    const int lin = blockIdx.x + KTILES * blockIdx.y;
    const int xcd = lin & 7;
    const int c   = lin >> 3;
    const int jb  = c & 31;
    const int mb  = xcd * 16 + (c >> 5);
    const int mbase = mb * 128;
    const int nbase = jb * 128;

    __shared__ __align__(16) unsigned short At[128 * 64];
    __shared__ __align__(16) unsigned short Bt[128 * 64];
    __shared__ float rowmin[128][2];

    const int t    = threadIdx.x;
    const int lane = t & 63;
    const int wid  = t >> 6;
    const int wr   = wid >> 1;
    const int wc   = wid & 1;

    const int lrow = lane >> 3;
    const int d8g  = (lane & 7) ^ lrow;

    f32x4 acc[4][4];
#pragma unroll
    for (int mi = 0; mi < 4; ++mi)
#pragma unroll
        for (int ni = 0; ni < 4; ++ni) acc[mi][ni] = (f32x4){0.f, 0.f, 0.f, 0.f};

    for (int k0 = 0; k0 < DIM; k0 += 64) {
#pragma unroll
        for (int i = 0; i < 4; ++i) {
            int rbase = wid * 32 + i * 8;
            int grow  = rbase + lrow;
            const unsigned short* ga =
                rh + (size_t)(mbase + grow) * DIM + k0 + d8g * 8;
            __builtin_amdgcn_global_load_lds(
                (glob_u32*)ga, (lds_u32*)&At[rbase * 64], 16, 0, 0);
            const unsigned short* gb =
                wh + (size_t)(nbase + grow) * DIM + k0 + d8g * 8;
            __builtin_amdgcn_global_load_lds(
                (glob_u32*)gb, (lds_u32*)&Bt[rbase * 64], 16, 0, 0);
        }
        __syncthreads();

#pragma unroll
        for (int kk = 0; kk < 2; ++kk) {
            bf16x8 af[4], bfr[4];
            const int g = kk * 4 + (lane >> 4);
#pragma unroll
            for (int mi = 0; mi < 4; ++mi) {
                int row = wr * 64 + mi * 16 + (lane & 15);
                af[mi] = *(const bf16x8*)&At[row * 64 + (g ^ (row & 7)) * 8];
            }
#pragma unroll
            for (int ni = 0; ni < 4; ++ni) {
                int row = wc * 64 + ni * 16 + (lane & 15);
                bfr[ni] = *(const bf16x8*)&Bt[row * 64 + (g ^ (row & 7)) * 8];
            }
#pragma unroll
            for (int mi = 0; mi < 4; ++mi)
#pragma unroll
                for (int ni = 0; ni < 4; ++ni)
                    acc[mi][ni] = __builtin_amdgcn_mfma_f32_16x16x32_bf16(
                        af[mi], bfr[ni], acc[mi][ni], 0, 0, 0);
        }
        __syncthreads();
    }

    int* scnt = (int*)Bt;
    unsigned long long* sbuf = (unsigned long long*)At;
    if (t < 128) {
        scnt[t] = 0;
        sbuf[t * CAP + 0] = EMPTY_E;
        sbuf[t * CAP + 1] = EMPTY_E;
    }

    // Pass 1: per-row tile min.
#pragma unroll
    for (int mi = 0; mi < 4; ++mi) {
#pragma unroll
        for (int reg = 0; reg < 4; ++reg) {
            int rloc = wr * 64 + mi * 16 + (lane >> 4) * 4 + reg;
            float rsqv = rsq[mbase + rloc];
            float m = INFINITY;
#pragma unroll
            for (int ni = 0; ni < 4; ++ni) {
                int kg = nbase + wc * 64 + ni * 16 + (lane & 15);
                float y;
                {
#pragma clang fp contract(off)
                    float t2 = 2.0f * acc[mi][ni][reg];
                    float u  = rsqv - t2;
                    y        = u + cb_sq[kg];
                }
                m = fminf(m, y);
            }
#pragma unroll
            for (int off = 1; off < 16; off <<= 1)
                m = fminf(m, __shfl_xor(m, off, 64));
            if ((lane & 15) == 0) rowmin[rloc][wc] = m;
        }
    }
    __syncthreads();

    // Pass 2: compact candidates with y <= tilemin + EPS.
#pragma unroll
    for (int mi = 0; mi < 4; ++mi) {
#pragma unroll
        for (int reg = 0; reg < 4; ++reg) {
            int rloc = wr * 64 + mi * 16 + (lane >> 4) * 4 + reg;
            float thrT = fminf(rowmin[rloc][0], rowmin[rloc][1]) + EPS;
            float rsqv = rsq[mbase + rloc];
#pragma unroll
            for (int ni = 0; ni < 4; ++ni) {
                int kg = nbase + wc * 64 + ni * 16 + (lane & 15);
                float y;
                {
#pragma clang fp contract(off)
                    float t2 = 2.0f * acc[mi][ni][reg];
                    float u  = rsqv - t2;
                    y        = u + cb_sq[kg];
                }
                if (y <= thrT) {
                    int pos = atomicAdd(&scnt[rloc], 1);
                    if (pos < CAP)
                        sbuf[rloc * CAP + pos] =
                            ((unsigned long long)__float_as_uint(y) << 32) |
                            (unsigned)kg;
                }
            }
        }
    }
    __syncthreads();

    if (t < 128) {
        part[(size_t)jb * N_ROWS + (mbase + t)] =
            fminf(rowmin[t][0], rowmin[t][1]);
        unsigned long long s0 = sbuf[t * CAP + 0];
        unsigned long long s1 = sbuf[t * CAP + 1];
        if (scnt[t] > CAP) s0 = OVFL_E;
        size_t bidx = ((size_t)jb * N_ROWS + (mbase + t)) * CAP;
        gbuf[bidx]     = s0;
        gbuf[bidx + 1] = s1;
    }
}

// Fused finish (r23 + dual-chain + early combine loads): 2048 blocks x 8 rows.
__global__ __launch_bounds__(256)
void finish_kernel(float* __restrict__ res,
                   const float* __restrict__ rin,
                   const float* __restrict__ cb,
                   const float* __restrict__ cb_sq,
                   float* __restrict__ rsq,
                   const float* __restrict__ part,
                   const unsigned long long* __restrict__ gbuf,
                   float* __restrict__ qout,
                   float* __restrict__ idx_out,
                   unsigned short* __restrict__ rh,
                   int stage, int do_next) {
#pragma clang fp contract(off)
    const int t   = threadIdx.x;
    const int jr  = t & 31;                  // tile index / lane-in-group
    const int rs  = t >> 5;                  // 0..7
    const int row0 = blockIdx.x * 8;
    const int row  = row0 + rs;

    __shared__ float partS[32][9];           // stride 9: conflict-free reads
    __shared__ ulonglong2 gbufS[32][8];

    {   // Coalesced slab staging: thread t -> tile t>>3, row-offset t&7.
        const int tile = t >> 3;
        const int ro   = t & 7;
        partS[tile][ro] = part[(size_t)tile * N_ROWS + row0 + ro];
        gbufS[tile][ro] =
            *(const ulonglong2*)&gbuf[((size_t)tile * N_ROWS + row0 + ro) * CAP];
    }

    // T14 early-issue: combine fragments of rr and qout (independent of
    // scan/chains); their HBM latency hides under the front phase.
    const float* rr = rin + (size_t)row * DIM;
    float*       qp = qout + (size_t)row * DIM;
    float4 rv4[4], qo4[4];
#pragma unroll
    for (int i = 0; i < 4; ++i)
        rv4[i] = *(const float4*)(rr + 4 * jr + 128 * i);
    if (stage != 0) {
#pragma unroll
        for (int i = 0; i < 4; ++i)
            qo4[i] = *(const float4*)(qp + 4 * jr + 128 * i);
    }
    __syncthreads();

    float pv = partS[jr][rs];
    float m = pv;
#pragma unroll
    for (int off = 1; off < 32; off <<= 1)
        m = fminf(m, __shfl_xor(m, off, 32));
    const float thr = m + EPS;

    ulonglong2 sv = gbufS[jr][rs];
    unsigned long long s0 = sv.x, s1 = sv.y;
    bool surv = (pv <= thr);
    if (!surv) { s0 = EMPTY_E; s1 = EMPTY_E; }
    const bool ovfl = surv && (s0 == OVFL_E);

    float y0 = __uint_as_float((unsigned)(s0 >> 32));   // EMPTY/OVFL -> NaN
    float y1 = __uint_as_float((unsigned)(s1 >> 32));
    unsigned long long p0 = (surv && !ovfl && (y0 <= thr)) ? s0 : EMPTY_E;
    unsigned long long p1 = (surv && !ovfl && (y1 <= thr)) ? s1 : EMPTY_E;

    // Per-lane top-2, then 5-step butterfly top-2 merge across the group.
    unsigned long long lm1 = p0 < p1 ? p0 : p1;
    unsigned long long lm2 = p0 < p1 ? p1 : p0;
    int oc = ovfl ? 1 : 0;
#pragma unroll
    for (int off = 1; off < 32; off <<= 1) {
        unsigned long long o1 =
            (unsigned long long)__shfl_xor((long long)lm1, off, 32);
        unsigned long long o2 =
            (unsigned long long)__shfl_xor((long long)lm2, off, 32);
        unsigned long long hi = lm1 > o1 ? lm1 : o1;
        unsigned long long lo2 = lm2 < o2 ? lm2 : o2;
        lm1 = lm1 < o1 ? lm1 : o1;
        lm2 = hi < lo2 ? hi : lo2;
        oc += __shfl_xor(oc, off, 32);
    }

    const float m1y = __uint_as_float((unsigned)(lm1 >> 32));
    const float m2y = __uint_as_float((unsigned)(lm2 >> 32));  // EMPTY -> NaN
    const bool shortcut = (oc == 0) && !(m2y <= m1y + GAPF);

    const float rsqv = rsq[row];

    unsigned long long lpk;
    if (shortcut) {
        lpk = lm1;                           // proven exact argmin
    } else {
        const float cth = (oc == 0) ? (m1y + GAPF) : thr;
        float by = INFINITY; int bk = 0x7fffffff;
        // Interleaved dual chain: both slots in ONE 512-iter loop.
        const bool c0 = surv && !ovfl && (y0 <= cth);
        const bool c1 = surv && !ovfl && (y1 <= cth);
        if (__any(c0 || c1)) {
            int k0 = c0 ? (int)(s0 & 0xFFFFFFFFull) : 0;
            int k1 = c1 ? (int)(s1 & 0xFFFFFFFFull) : 0;
            const float* wp0 = cb + (size_t)k0 * DIM;
            const float* wp1 = cb + (size_t)k1 * DIM;
            float dot0 = 0.0f, dot1 = 0.0f;  // exact chains, d ascending
#pragma unroll 8
            for (int d = 0; d < DIM; d += 4) {
                float4 r4  = *(const float4*)(rr + d);
                float4 w40 = *(const float4*)(wp0 + d);
                float4 w41 = *(const float4*)(wp1 + d);
                dot0 = fmaf(r4.x, w40.x, dot0);
                dot0 = fmaf(r4.y, w40.y, dot0);
                dot0 = fmaf(r4.z, w40.z, dot0);
                dot0 = fmaf(r4.w, w40.w, dot0);
                dot1 = fmaf(r4.x, w41.x, dot1);
                dot1 = fmaf(r4.y, w41.y, dot1);
                dot1 = fmaf(r4.z, w41.z, dot1);
                dot1 = fmaf(r4.w, w41.w, dot1);
            }
            if (c0) {
                float t2 = 2.0f * dot0;
                float u  = rsqv - t2;
                float y  = u + cb_sq[k0];
                if (y < by || (y == by && k0 < bk)) { by = y; bk = k0; }
            }
            if (c1) {
                float t2 = 2.0f * dot1;
                float u  = rsqv - t2;
                float y  = u + cb_sq[k1];
                if (y < by || (y == by && k1 < bk)) { by = y; bk = k1; }
            }
        }
        // Overflow tiles: full-tile exact recheck by the whole 32-lane group.
        unsigned grp = (unsigned)(__ballot(ovfl) >> (t & 32));
        while (grp) {
            int jt = __builtin_ctz(grp);
            grp &= grp - 1;
#pragma unroll
            for (int q = 0; q < 4; ++q) {
                int k = jt * 128 + jr * 4 + q;
                const float* wp = cb + (size_t)k * DIM;
                float dot = 0.0f;            // exact chain, d ascending
#pragma unroll 8
                for (int d = 0; d < DIM; d += 4) {
                    float4 r4 = *(const float4*)(rr + d);
                    float4 w4 = *(const float4*)(wp + d);
                    dot = fmaf(r4.x, w4.x, dot);
                    dot = fmaf(r4.y, w4.y, dot);
                    dot = fmaf(r4.z, w4.z, dot);
                    dot = fmaf(r4.w, w4.w, dot);
                }
                float t2 = 2.0f * dot;
                float u  = rsqv - t2;
                float y  = u + cb_sq[k];
                if (y < by || (y == by && k < bk)) { by = y; bk = k; }
            }
        }
        lpk = ((unsigned long long)__float_as_uint(by) << 32) | (unsigned)bk;
#pragma unroll
        for (int off = 1; off < 32; off <<= 1) {
            unsigned long long o =
                (unsigned long long)__shfl_xor((long long)lpk, off, 32);
            if (o < lpk) lpk = o;
        }
    }

    const int bi = (int)(lpk & 0xFFFFFFFFull);
    if (jr == 0) idx_out[(size_t)row * NUM_STAGES + stage] = (float)bi;

    // Fused combine (float4): lane jr owns d = 4*jr + 128*i, i = 0..3.
    const float* wp = cb + (size_t)bi * DIM;
    float*       rp = res + (size_t)row * DIM;
    unsigned short* rhp = rh + (size_t)row * DIM;

    float4 rn4[4];
#pragma unroll
    for (int i = 0; i < 4; ++i) {
        int d0 = 4 * jr + 128 * i;
        float4 wv = *(const float4*)(wp + d0);
        float4 rv = rv4[i];
        float4 qs, rn;
        qs.x = rv.x + (wv.x - rv.x);  rn.x = rv.x - qs.x;
        qs.y = rv.y + (wv.y - rv.y);  rn.y = rv.y - qs.y;
        qs.z = rv.z + (wv.z - rv.z);  rn.z = rv.z - qs.z;
        qs.w = rv.w + (wv.w - rv.w);  rn.w = rv.w - qs.w;
        rn4[i] = rn;
        if (do_next) {
            *(float4*)(rp + d0) = rn;
            ushort4 h;
            h.x = f2bf(rn.x); h.y = f2bf(rn.y);
            h.z = f2bf(rn.z); h.w = f2bf(rn.w);
            *(ushort4*)(rhp + d0) = h;
        }
        if (stage == 0) {
            *(float4*)(qp + d0) = qs;
        } else {
            float4 qo = qo4[i];
            qo.x = qo.x + qs.x; qo.y = qo.y + qs.y;
            qo.z = qo.z + qs.z; qo.w = qo.w + qs.w;
            *(float4*)(qp + d0) = qo;
        }
    }

    if (do_next) {
        // 32-lane float4-mapping pairwise tree (DAG-identical, r20-proven).
        float P[4];
#pragma unroll
        for (int b = 0; b < 4; ++b) {
            float4 v = rn4[b];
            float sqx = v.x * v.x, sqy = v.y * v.y;
            float sqz = v.z * v.z, sqw = v.w * v.w;
            float Rx = sqx + __shfl_down(sqx, 16, 32);
            float Ry = sqy + __shfl_down(sqy, 16, 32);
            float Rz = sqz + __shfl_down(sqz, 16, 32);
            float Rw = sqw + __shfl_down(sqw, 16, 32);
            float tx = Rx + __shfl_down(Rx, 4, 32);
            float ty = Ry + __shfl_down(Ry, 4, 32);
            float tz = Rz + __shfl_down(Rz, 4, 32);
            float tw = Rw + __shfl_down(Rw, 4, 32);
            float ux = tx + __shfl_down(tx, 8, 32);
            float uy = ty + __shfl_down(ty, 8, 32);
            float uz = tz + __shfl_down(tz, 8, 32);
            float uw = tw + __shfl_down(tw, 8, 32);
            float ax = ux + __shfl_down(ux, 2, 32);
            float ay = uy + __shfl_down(uy, 2, 32);
            float az = uz + __shfl_down(uz, 2, 32);
            float aw = uw + __shfl_down(uw, 2, 32);
            float cx = ax + __shfl_down(ax, 1, 32);
            float cy = ay + __shfl_down(ay, 1, 32);
            float cz = az + __shfl_down(az, 1, 32);
            float cw = aw + __shfl_down(aw, 1, 32);
            float d0 = cx + cz;
            float d1 = cy + cw;
            P[b] = d0 + d1;
        }
        float s01 = P[0] + P[1];
        float s23 = P[2] + P[3];
        if (jr == 0) rsq[row] = s01 + s23;
    }
}

extern "C" void kernel_launch(void* const* d_in, const int* in_sizes, int n_in,
                              void* d_out, int out_size, void* d_ws, size_t ws_size,
                              hipStream_t stream) {
    const float* input = (const float*)d_in[0];
    const float* cb    = (const float*)d_in[1];

    float* out_f   = (float*)d_out;
    float* qout    = out_f + Q_OFF;
    float* idx_out = out_f + IDX_OFF;
    float* loss    = out_f + LOSS_OFF;

    char* ws = (char*)d_ws;
    float*          residual = (float*)(ws + RES_OFF);
    unsigned short* rh       = (unsigned short*)(ws + RH_OFF);
    unsigned short* wh       = (unsigned short*)(ws + WH_OFF);
    float*          cb_sq    = (float*)(ws + CBSQ_OFF);
    float*          rsq      = (float*)(ws + RSQ_OFF);
    float*          part     = (float*)(ws + PART_OFF);
    unsigned long long* gbuf = (unsigned long long*)(ws + GBUF_OFF);

    setup_kernel<<<1024 + N_ROWS / 4, 256, 0, stream>>>(
        cb, cb_sq, wh, loss, input, rh, rsq);

    for (int s = 0; s < NUM_STAGES; ++s) {
        const float* rin = (s == 0) ? input : residual;
        passA_kernel<<<dim3(KTILES, N_ROWS / 128), 256, 0, stream>>>(
            rh, wh, cb_sq, rsq, part, gbuf);
        finish_kernel<<<N_ROWS / 8, 256, 0, stream>>>(
            residual, rin, cb, cb_sq, rsq, part, gbuf,
            qout, idx_out, rh, s, (s < NUM_STAGES - 1) ? 1 : 0);
    }
}

// Round 25
// 818.867 us; speedup vs baseline: 1.0960x; 1.0960x over previous
//
#include <hip/hip_runtime.h>
#include <math.h>

// Residual VQ, 4 stages, N=16384 rows, D=512, K=4096.
// Round 25: REVERT to r23 verbatim (session best: 820.6us, PASSED absmax=0).
// r24's prefetch+dual-chain raised VGPR 48->68 -> occupancy 22->12% -> finish
// 105->126us (occupancy-elastic kernel; VGPR-neutral edits only).
// Final structure: MFMA candidate filter (passA: 128x128 bf16 GEMM via
// global_load_lds + XOR swizzle, XCD-aware blocks, epilogue compaction
// CAP=2 + tile-min) -> fused finish (slab-staged scan, gap shortcut
// [>= 2*delta proof], inline exact chains, inline overflow recheck,
// width-32 lex reduce, float4 combine + 32-lane pairwise rsq tree).
// Exact-math invariants (verified rounds 3-23): one fmaf per d, d=0..511
// ascending, per output; epilogue fl(fl(rsq-fl(2*dot))+cbsq) uncontracted;
// first-index ties; numpy pairwise rsq/cbsq tree; exact residual/q_ste chain.

namespace {
constexpr int N_ROWS     = 16384;
constexpr int DIM        = 512;
constexpr int K_CODES    = 4096;
constexpr int NUM_STAGES = 4;

constexpr int KTILES = 32;            // 128 codes per tile
constexpr float EPS  = 1e-3f;         // compaction margin (proven rounds 7-23)
constexpr float GAPF = 6e-4f;         // >= 2*delta shortcut gap (delta<=2.7e-4)
constexpr int CAP    = 2;             // compacted candidates per (row,tile)

// d_out layout (all read back as float32):
constexpr size_t Q_OFF    = 0;
constexpr size_t IDX_OFF  = (size_t)N_ROWS * DIM;                  // 8388608
constexpr size_t LOSS_OFF = IDX_OFF + (size_t)N_ROWS * NUM_STAGES; // 8454144

// ws layout (bytes), total ~62.3 MB:
constexpr size_t RES_OFF  = 0;                                    // 32 MB fp32 residual
constexpr size_t RH_OFF   = (size_t)N_ROWS * DIM * 4;             // +16 MB bf16 residual
constexpr size_t WH_OFF   = RH_OFF + (size_t)N_ROWS * DIM * 2;    // +4 MB bf16 codebook
constexpr size_t CBSQ_OFF = WH_OFF + (size_t)K_CODES * DIM * 2;   // +16 KB
constexpr size_t RSQ_OFF  = CBSQ_OFF + (size_t)K_CODES * 4;       // +64 KB
constexpr size_t PART_OFF = RSQ_OFF + (size_t)N_ROWS * 4;         // +2 MB tile mins [tile][row]
constexpr size_t GBUF_OFF = PART_OFF + (size_t)N_ROWS * KTILES * 4; // +8 MB [tile][row][CAP]

constexpr unsigned long long EMPTY_E = 0xFFFFFFFFFFFFFFFFull;
constexpr unsigned long long OVFL_E  = 0xFFFFFFFFFFFFFFFEull;
} // namespace

typedef short bf16x8 __attribute__((ext_vector_type(8)));
typedef float f32x4  __attribute__((ext_vector_type(4)));

typedef __attribute__((address_space(1))) const unsigned int glob_u32;
typedef __attribute__((address_space(3))) unsigned int lds_u32;

__device__ __forceinline__ unsigned short f2bf(float x) {   // RNE fp32->bf16
    unsigned int u = __float_as_uint(x);
    return (unsigned short)((u + 0x7fffu + ((u >> 16) & 1u)) >> 16);
}

// Register-based exact pairwise tree (64-lane): v8[i] = row[lane + i*64].
__device__ __forceinline__ float rowsq_tree(const float v8[8], int lane) {
#pragma clang fp contract(off)
    float P[4];
#pragma unroll
    for (int b = 0; b < 4; ++b) {
        float xa = v8[2 * b];
        float xb = v8[2 * b + 1];
        float sa = xa * xa;
        float sb = xb * xb;
        float R  = sa + sb;
        float t  = R + __shfl_down(R, 16, 64);
        float u  = t + __shfl_down(t, 32, 64);
        float a  = u + __shfl_down(u, 8, 64);
        float c  = a + __shfl_down(a, 4, 64);
        float d  = c + __shfl_down(c, 2, 64);
        P[b]     = d + __shfl_down(d, 1, 64);
    }
    float s01 = P[0] + P[1];
    float s23 = P[2] + P[3];
    return s01 + s23;
}

// Setup (fused): blocks 0..1023 -> cbsq + bf16 codebook; 1024..5119 -> init.
__global__ __launch_bounds__(256)
void setup_kernel(const float* __restrict__ cb, float* __restrict__ cb_sq,
                  unsigned short* __restrict__ wh, float* __restrict__ loss,
                  const float* __restrict__ input,
                  unsigned short* __restrict__ rh, float* __restrict__ rsq) {
    const int t    = threadIdx.x;
    const int lane = t & 63;
    const int sub  = t >> 6;
    if (blockIdx.x < 1024) {
        int k = blockIdx.x * 4 + sub;
        const float* row = cb + (size_t)k * DIM;
        unsigned short* whp = wh + (size_t)k * DIM;
        float v8[8];
#pragma unroll
        for (int i = 0; i < 8; ++i) {
            float v = row[lane + i * 64];
            v8[i] = v;
            whp[lane + i * 64] = f2bf(v);
        }
        float s = rowsq_tree(v8, lane);
        if (lane == 0) cb_sq[k] = s;
        if (k == 0 && lane == 0) *loss = 0.0f;
    } else {
        int row = (blockIdx.x - 1024) * 4 + sub;
        const float* x = input + (size_t)row * DIM;
        unsigned short* rhp = rh + (size_t)row * DIM;
        float v8[8];
#pragma unroll
        for (int i = 0; i < 8; ++i) {
            int d = lane + i * 64;
            float v = x[d];
            v8[i] = v;
            rhp[d] = f2bf(v);
        }
        float s = rowsq_tree(v8, lane);
        if (lane == 0) rsq[row] = s;
    }
}

// Pass A (r18-verbatim): 128x128x(BK=64) bf16 MFMA GEMM via global_load_lds
// with pre-swizzled source + XOR frag reads; epilogue candidate compaction.
__global__ __launch_bounds__(256, 2)
void passA_kernel(const unsigned short* __restrict__ rh,
                  const unsigned short* __restrict__ wh,
                  const float* __restrict__ cb_sq,
                  const float* __restrict__ rsq,
                  float* __restrict__ part,
                  unsigned long long* __restrict__ gbuf) {
    const int lin = blockIdx.x + KTILES * blockIdx.y;
    const int xcd = lin & 7;
    const int c   = lin >> 3;
    const int jb  = c & 31;
    const int mb  = xcd * 16 + (c >> 5);
    const int mbase = mb * 128;
    const int nbase = jb * 128;

    __shared__ __align__(16) unsigned short At[128 * 64];
    __shared__ __align__(16) unsigned short Bt[128 * 64];
    __shared__ float rowmin[128][2];

    const int t    = threadIdx.x;
    const int lane = t & 63;
    const int wid  = t >> 6;
    const int wr   = wid >> 1;
    const int wc   = wid & 1;

    const int lrow = lane >> 3;
    const int d8g  = (lane & 7) ^ lrow;

    f32x4 acc[4][4];
#pragma unroll
    for (int mi = 0; mi < 4; ++mi)
#pragma unroll
        for (int ni = 0; ni < 4; ++ni) acc[mi][ni] = (f32x4){0.f, 0.f, 0.f, 0.f};

    for (int k0 = 0; k0 < DIM; k0 += 64) {
#pragma unroll
        for (int i = 0; i < 4; ++i) {
            int rbase = wid * 32 + i * 8;
            int grow  = rbase + lrow;
            const unsigned short* ga =
                rh + (size_t)(mbase + grow) * DIM + k0 + d8g * 8;
            __builtin_amdgcn_global_load_lds(
                (glob_u32*)ga, (lds_u32*)&At[rbase * 64], 16, 0, 0);
            const unsigned short* gb =
                wh + (size_t)(nbase + grow) * DIM + k0 + d8g * 8;
            __builtin_amdgcn_global_load_lds(
                (glob_u32*)gb, (lds_u32*)&Bt[rbase * 64], 16, 0, 0);
        }
        __syncthreads();

#pragma unroll
        for (int kk = 0; kk < 2; ++kk) {
            bf16x8 af[4], bfr[4];
            const int g = kk * 4 + (lane >> 4);
#pragma unroll
            for (int mi = 0; mi < 4; ++mi) {
                int row = wr * 64 + mi * 16 + (lane & 15);
                af[mi] = *(const bf16x8*)&At[row * 64 + (g ^ (row & 7)) * 8];
            }
#pragma unroll
            for (int ni = 0; ni < 4; ++ni) {
                int row = wc * 64 + ni * 16 + (lane & 15);
                bfr[ni] = *(const bf16x8*)&Bt[row * 64 + (g ^ (row & 7)) * 8];
            }
#pragma unroll
            for (int mi = 0; mi < 4; ++mi)
#pragma unroll
                for (int ni = 0; ni < 4; ++ni)
                    acc[mi][ni] = __builtin_amdgcn_mfma_f32_16x16x32_bf16(
                        af[mi], bfr[ni], acc[mi][ni], 0, 0, 0);
        }
        __syncthreads();
    }

    int* scnt = (int*)Bt;
    unsigned long long* sbuf = (unsigned long long*)At;
    if (t < 128) {
        scnt[t] = 0;
        sbuf[t * CAP + 0] = EMPTY_E;
        sbuf[t * CAP + 1] = EMPTY_E;
    }

    // Pass 1: per-row tile min.
#pragma unroll
    for (int mi = 0; mi < 4; ++mi) {
#pragma unroll
        for (int reg = 0; reg < 4; ++reg) {
            int rloc = wr * 64 + mi * 16 + (lane >> 4) * 4 + reg;
            float rsqv = rsq[mbase + rloc];
            float m = INFINITY;
#pragma unroll
            for (int ni = 0; ni < 4; ++ni) {
                int kg = nbase + wc * 64 + ni * 16 + (lane & 15);
                float y;
                {
#pragma clang fp contract(off)
                    float t2 = 2.0f * acc[mi][ni][reg];
                    float u  = rsqv - t2;
                    y        = u + cb_sq[kg];
                }
                m = fminf(m, y);
            }
#pragma unroll
            for (int off = 1; off < 16; off <<= 1)
                m = fminf(m, __shfl_xor(m, off, 64));
            if ((lane & 15) == 0) rowmin[rloc][wc] = m;
        }
    }
    __syncthreads();

    // Pass 2: compact candidates with y <= tilemin + EPS.
#pragma unroll
    for (int mi = 0; mi < 4; ++mi) {
#pragma unroll
        for (int reg = 0; reg < 4; ++reg) {
            int rloc = wr * 64 + mi * 16 + (lane >> 4) * 4 + reg;
            float thrT = fminf(rowmin[rloc][0], rowmin[rloc][1]) + EPS;
            float rsqv = rsq[mbase + rloc];
#pragma unroll
            for (int ni = 0; ni < 4; ++ni) {
                int kg = nbase + wc * 64 + ni * 16 + (lane & 15);
                float y;
                {
#pragma clang fp contract(off)
                    float t2 = 2.0f * acc[mi][ni][reg];
                    float u  = rsqv - t2;
                    y        = u + cb_sq[kg];
                }
                if (y <= thrT) {
                    int pos = atomicAdd(&scnt[rloc], 1);
                    if (pos < CAP)
                        sbuf[rloc * CAP + pos] =
                            ((unsigned long long)__float_as_uint(y) << 32) |
                            (unsigned)kg;
                }
            }
        }
    }
    __syncthreads();

    if (t < 128) {
        part[(size_t)jb * N_ROWS + (mbase + t)] =
            fminf(rowmin[t][0], rowmin[t][1]);
        unsigned long long s0 = sbuf[t * CAP + 0];
        unsigned long long s1 = sbuf[t * CAP + 1];
        if (scnt[t] > CAP) s0 = OVFL_E;
        size_t bidx = ((size_t)jb * N_ROWS + (mbase + t)) * CAP;
        gbuf[bidx]     = s0;
        gbuf[bidx + 1] = s1;
    }
}

// Fused finish (r22 + gap shortcut): 2048 blocks x 8 rows; slab staging,
// top-2 butterfly -> gap test (subsumes count-1) -> chains only when
// top-2 approx gap <= GAPF, restricted to y^ <= y^_1 + GAPF; overflow rows
// keep full r22 path; width-32 lex reduce; float4 combine + rsq tree.
__global__ __launch_bounds__(256)
void finish_kernel(float* __restrict__ res,
                   const float* __restrict__ rin,
                   const float* __restrict__ cb,
                   const float* __restrict__ cb_sq,
                   float* __restrict__ rsq,
                   const float* __restrict__ part,
                   const unsigned long long* __restrict__ gbuf,
                   float* __restrict__ qout,
                   float* __restrict__ idx_out,
                   unsigned short* __restrict__ rh,
                   int stage, int do_next) {
#pragma clang fp contract(off)
    const int t   = threadIdx.x;
    const int jr  = t & 31;                  // tile index / lane-in-group
    const int rs  = t >> 5;                  // 0..7
    const int row0 = blockIdx.x * 8;
    const int row  = row0 + rs;

    __shared__ float partS[32][9];           // stride 9: conflict-free reads
    __shared__ ulonglong2 gbufS[32][8];

    {   // Coalesced slab staging: thread t -> tile t>>3, row-offset t&7.
        const int tile = t >> 3;
        const int ro   = t & 7;
        partS[tile][ro] = part[(size_t)tile * N_ROWS + row0 + ro];
        gbufS[tile][ro] =
            *(const ulonglong2*)&gbuf[((size_t)tile * N_ROWS + row0 + ro) * CAP];
    }
    __syncthreads();

    float pv = partS[jr][rs];
    float m = pv;
#pragma unroll
    for (int off = 1; off < 32; off <<= 1)
        m = fminf(m, __shfl_xor(m, off, 32));
    const float thr = m + EPS;

    ulonglong2 sv = gbufS[jr][rs];
    unsigned long long s0 = sv.x, s1 = sv.y;
    bool surv = (pv <= thr);
    if (!surv) { s0 = EMPTY_E; s1 = EMPTY_E; }
    const bool ovfl = surv && (s0 == OVFL_E);

    // Qualifying packed slots (EMPTY if not). Packed u64 order == (y,k) order.
    float y0 = __uint_as_float((unsigned)(s0 >> 32));   // EMPTY/OVFL -> NaN
    float y1 = __uint_as_float((unsigned)(s1 >> 32));
    unsigned long long p0 = (surv && !ovfl && (y0 <= thr)) ? s0 : EMPTY_E;
    unsigned long long p1 = (surv && !ovfl && (y1 <= thr)) ? s1 : EMPTY_E;

    // Per-lane top-2, then 5-step butterfly top-2 merge across the group.
    unsigned long long lm1 = p0 < p1 ? p0 : p1;
    unsigned long long lm2 = p0 < p1 ? p1 : p0;
    int oc = ovfl ? 1 : 0;
#pragma unroll
    for (int off = 1; off < 32; off <<= 1) {
        unsigned long long o1 =
            (unsigned long long)__shfl_xor((long long)lm1, off, 32);
        unsigned long long o2 =
            (unsigned long long)__shfl_xor((long long)lm2, off, 32);
        unsigned long long hi = lm1 > o1 ? lm1 : o1;
        unsigned long long lo2 = lm2 < o2 ? lm2 : o2;
        lm1 = lm1 < o1 ? lm1 : o1;
        lm2 = hi < lo2 ? hi : lo2;
        oc += __shfl_xor(oc, off, 32);
    }

    const float m1y = __uint_as_float((unsigned)(lm1 >> 32));
    const float m2y = __uint_as_float((unsigned)(lm2 >> 32));  // EMPTY -> NaN
    // Shortcut: no overflow AND (single candidate OR top-2 gap > GAPF).
    // NaN m2y makes (m2y <= m1y+GAPF) false -> shortcut true.
    const bool shortcut = (oc == 0) && !(m2y <= m1y + GAPF);

    const float* rr  = rin + (size_t)row * DIM;
    const float rsqv = rsq[row];

    unsigned long long lpk;
    if (shortcut) {
        lpk = lm1;                           // proven exact argmin
    } else {
        // Chain threshold: tight when no overflow (contains argmin + ties),
        // conservative (thr) when overflow present.
        const float cth = (oc == 0) ? (m1y + GAPF) : thr;
        float by = INFINITY; int bk = 0x7fffffff;
        if (surv && !ovfl) {
#pragma unroll
            for (int sl = 0; sl < CAP; ++sl) {
                unsigned long long s = sl ? s1 : s0;
                float yh = __uint_as_float((unsigned)(s >> 32));
                if (!(yh <= cth)) continue;  // EMPTY -> NaN -> skipped
                int k = (int)(s & 0xFFFFFFFFull);
                const float* wp = cb + (size_t)k * DIM;
                float dot = 0.0f;            // exact chain, d ascending
#pragma unroll 8
                for (int d = 0; d < DIM; d += 4) {
                    float4 r4 = *(const float4*)(rr + d);
                    float4 w4 = *(const float4*)(wp + d);
                    dot = fmaf(r4.x, w4.x, dot);
                    dot = fmaf(r4.y, w4.y, dot);
                    dot = fmaf(r4.z, w4.z, dot);
                    dot = fmaf(r4.w, w4.w, dot);
                }
                float t2 = 2.0f * dot;
                float u  = rsqv - t2;
                float y  = u + cb_sq[k];
                if (y < by || (y == by && k < bk)) { by = y; bk = k; }
            }
        }
        // Overflow tiles: full-tile exact recheck by the whole 32-lane group.
        unsigned grp = (unsigned)(__ballot(ovfl) >> (t & 32));
        while (grp) {
            int jt = __builtin_ctz(grp);
            grp &= grp - 1;
#pragma unroll
            for (int q = 0; q < 4; ++q) {
                int k = jt * 128 + jr * 4 + q;
                const float* wp = cb + (size_t)k * DIM;
                float dot = 0.0f;            // exact chain, d ascending
#pragma unroll 8
                for (int d = 0; d < DIM; d += 4) {
                    float4 r4 = *(const float4*)(rr + d);
                    float4 w4 = *(const float4*)(wp + d);
                    dot = fmaf(r4.x, w4.x, dot);
                    dot = fmaf(r4.y, w4.y, dot);
                    dot = fmaf(r4.z, w4.z, dot);
                    dot = fmaf(r4.w, w4.w, dot);
                }
                float t2 = 2.0f * dot;
                float u  = rsqv - t2;
                float y  = u + cb_sq[k];
                if (y < by || (y == by && k < bk)) { by = y; bk = k; }
            }
        }
        lpk = ((unsigned long long)__float_as_uint(by) << 32) | (unsigned)bk;
        // Width-32 lexicographic min; butterfly -> all lanes hold the result.
#pragma unroll
        for (int off = 1; off < 32; off <<= 1) {
            unsigned long long o =
                (unsigned long long)__shfl_xor((long long)lpk, off, 32);
            if (o < lpk) lpk = o;
        }
    }

    const int bi = (int)(lpk & 0xFFFFFFFFull);
    if (jr == 0) idx_out[(size_t)row * NUM_STAGES + stage] = (float)bi;

    // Fused combine (float4): lane jr owns d = 4*jr + 128*i, i = 0..3.
    const float* wp = cb + (size_t)bi * DIM;
    float*       rp = res + (size_t)row * DIM;
    float*       qp = qout + (size_t)row * DIM;
    unsigned short* rhp = rh + (size_t)row * DIM;

    float4 rn4[4];
#pragma unroll
    for (int i = 0; i < 4; ++i) {
        int d0 = 4 * jr + 128 * i;
        float4 wv = *(const float4*)(wp + d0);
        float4 rv = *(const float4*)(rr + d0);
        float4 qs, rn;
        qs.x = rv.x + (wv.x - rv.x);  rn.x = rv.x - qs.x;
        qs.y = rv.y + (wv.y - rv.y);  rn.y = rv.y - qs.y;
        qs.z = rv.z + (wv.z - rv.z);  rn.z = rv.z - qs.z;
        qs.w = rv.w + (wv.w - rv.w);  rn.w = rv.w - qs.w;
        rn4[i] = rn;
        if (do_next) {
            *(float4*)(rp + d0) = rn;
            ushort4 h;
            h.x = f2bf(rn.x); h.y = f2bf(rn.y);
            h.z = f2bf(rn.z); h.w = f2bf(rn.w);
            *(ushort4*)(rhp + d0) = h;
        }
        if (stage == 0) {
            *(float4*)(qp + d0) = qs;
        } else {
            float4 qo = *(const float4*)(qp + d0);
            qo.x = qo.x + qs.x; qo.y = qo.y + qs.y;
            qo.z = qo.z + qs.z; qo.w = qo.w + qs.w;
            *(float4*)(qp + d0) = qo;
        }
    }

    if (do_next) {
        // 32-lane float4-mapping pairwise tree (DAG-identical, r20-proven).
        float P[4];
#pragma unroll
        for (int b = 0; b < 4; ++b) {
            float4 v = rn4[b];
            float sqx = v.x * v.x, sqy = v.y * v.y;
            float sqz = v.z * v.z, sqw = v.w * v.w;
            float Rx = sqx + __shfl_down(sqx, 16, 32);
            float Ry = sqy + __shfl_down(sqy, 16, 32);
            float Rz = sqz + __shfl_down(sqz, 16, 32);
            float Rw = sqw + __shfl_down(sqw, 16, 32);
            float tx = Rx + __shfl_down(Rx, 4, 32);
            float ty = Ry + __shfl_down(Ry, 4, 32);
            float tz = Rz + __shfl_down(Rz, 4, 32);
            float tw = Rw + __shfl_down(Rw, 4, 32);
            float ux = tx + __shfl_down(tx, 8, 32);
            float uy = ty + __shfl_down(ty, 8, 32);
            float uz = tz + __shfl_down(tz, 8, 32);
            float uw = tw + __shfl_down(tw, 8, 32);
            float ax = ux + __shfl_down(ux, 2, 32);
            float ay = uy + __shfl_down(uy, 2, 32);
            float az = uz + __shfl_down(uz, 2, 32);
            float aw = uw + __shfl_down(uw, 2, 32);
            float cx = ax + __shfl_down(ax, 1, 32);
            float cy = ay + __shfl_down(ay, 1, 32);
            float cz = az + __shfl_down(az, 1, 32);
            float cw = aw + __shfl_down(aw, 1, 32);
            float d0 = cx + cz;
            float d1 = cy + cw;
            P[b] = d0 + d1;
        }
        float s01 = P[0] + P[1];
        float s23 = P[2] + P[3];
        if (jr == 0) rsq[row] = s01 + s23;
    }
}

extern "C" void kernel_launch(void* const* d_in, const int* in_sizes, int n_in,
                              void* d_out, int out_size, void* d_ws, size_t ws_size,
                              hipStream_t stream) {
    const float* input = (const float*)d_in[0];
    const float* cb    = (const float*)d_in[1];

    float* out_f   = (float*)d_out;
    float* qout    = out_f + Q_OFF;
    float* idx_out = out_f + IDX_OFF;
    float* loss    = out_f + LOSS_OFF;

    char* ws = (char*)d_ws;
    float*          residual = (float*)(ws + RES_OFF);
    unsigned short* rh       = (unsigned short*)(ws + RH_OFF);
    unsigned short* wh       = (unsigned short*)(ws + WH_OFF);
    float*          cb_sq    = (float*)(ws + CBSQ_OFF);
    float*          rsq      = (float*)(ws + RSQ_OFF);
    float*          part     = (float*)(ws + PART_OFF);
    unsigned long long* gbuf = (unsigned long long*)(ws + GBUF_OFF);

    setup_kernel<<<1024 + N_ROWS / 4, 256, 0, stream>>>(
        cb, cb_sq, wh, loss, input, rh, rsq);

    for (int s = 0; s < NUM_STAGES; ++s) {
        const float* rin = (s == 0) ? input : residual;
        passA_kernel<<<dim3(KTILES, N_ROWS / 128), 256, 0, stream>>>(
            rh, wh, cb_sq, rsq, part, gbuf);
        finish_kernel<<<N_ROWS / 8, 256, 0, stream>>>(
            residual, rin, cb, cb_sq, rsq, part, gbuf,
            qout, idx_out, rh, s, (s < NUM_STAGES - 1) ? 1 : 0);
    }
}